// Round 15
// baseline (286.057 us; speedup 1.0000x reference)
//
#include <hip/hip_runtime.h>
#include <hip/hip_bf16.h>

typedef __attribute__((ext_vector_type(8))) __bf16 bf16x8;
typedef __attribute__((ext_vector_type(4))) float f32x4;

#define DEV static __device__ __forceinline__

DEV unsigned short f2bf(float f) {
  __bf16 h = (__bf16)f;
  union { __bf16 h; unsigned short u; } v; v.h = h;
  return v.u;
}
DEV float bf2f(unsigned short h) {
  union { unsigned int u; float f; } v; v.u = ((unsigned int)h) << 16;
  return v.f;
}
DEV unsigned pkbf(float lo, float hi) {
  union { __bf16 h[2]; unsigned u; } v;
  v.h[0] = (__bf16)lo; v.h[1] = (__bf16)hi;
  return v.u;
}
DEV f32x4 mfma16(bf16x8 a, bf16x8 b, f32x4 c) {
  return __builtin_amdgcn_mfma_f32_16x16x32_bf16(a, b, c, 0, 0, 0);
}
DEV void gload_lds16(const void* g, void* l) {
  __builtin_amdgcn_global_load_lds((__attribute__((address_space(1))) void*)g,
                                   (__attribute__((address_space(3))) void*)l,
                                   16, 0, 0);
}
DEV float fexp2(float x) { return exp2f(x); }

// ---------------- fused f32 -> bf16 convert of all 7 weights ----------------
// regions: 0 q_w 1 k_w 2 v_w 3 o_w 4 w2 (linear) | 5 w1, 6 w3 (row-interleaved into w13)
struct CvtArgs { const float* src[7]; int cum[8]; };
__global__ __launch_bounds__(256) void cvt_all(CvtArgs a, unsigned short* __restrict__ dst) {
  int i = (blockIdx.x * 256 + threadIdx.x) * 4;
  if (i >= a.cum[7]) return;
  int w = 0;
#pragma unroll 7
  for (int t = 0; t < 7; ++t) if (i >= a.cum[t + 1]) w = t + 1;
  int local = i - a.cum[w];
  int di;
  if (w == 5)      di = 8388608 + ((local >> 10) << 11) + (local & 1023);          // w1 -> row 2f
  else if (w == 6) di = 8388608 + ((local >> 10) << 11) + 1024 + (local & 1023);   // w3 -> row 2f+1
  else             di = i;
  float4 v = *(const float4*)(a.src[w] + local);
  dst[di + 0] = f2bf(v.x);
  dst[di + 1] = f2bf(v.y);
  dst[di + 2] = f2bf(v.z);
  dst[di + 3] = f2bf(v.w);
}

// ---------------- RMSNorm: fp32 in -> bf16 out (D=1024) ----------------
__global__ __launch_bounds__(256) void rmsnorm_k(const float* __restrict__ x,
                                                 const float* __restrict__ w,
                                                 unsigned short* __restrict__ out) {
  int row = blockIdx.x;
  int tid = threadIdx.x;
  const float* xr = x + (size_t)row * 1024;
  float4 v = *(const float4*)(xr + tid * 4);
  float ss = v.x * v.x + v.y * v.y + v.z * v.z + v.w * v.w;
#pragma unroll
  for (int m = 32; m >= 1; m >>= 1) ss += __shfl_xor(ss, m);
  __shared__ float red[4];
  int wid = tid >> 6;
  if ((tid & 63) == 0) red[wid] = ss;
  __syncthreads();
  float tot = red[0] + red[1] + red[2] + red[3];
  float rs = rsqrtf(tot * (1.0f / 1024.0f) + 1e-5f);
  float4 wv = *(const float4*)(w + tid * 4);
  unsigned short* o = out + (size_t)row * 1024 + tid * 4;
  o[0] = f2bf(v.x * rs * wv.x);
  o[1] = f2bf(v.y * rs * wv.y);
  o[2] = f2bf(v.z * rs * wv.z);
  o[3] = f2bf(v.w * rs * wv.w);
}

// ---------------- RoPE in-place: one thread rotates q AND k ----------------
__global__ __launch_bounds__(256) void rope2_k(unsigned short* __restrict__ q,
                                               unsigned short* __restrict__ k,
                                               const int* __restrict__ pos) {
  int idx = blockIdx.x * 256 + threadIdx.x;  // 2,097,152 threads
  int i = idx & 31;
  int s = (idx >> 5) & 2047;
  int bh = idx >> 16;
  int b = bh >> 4;
  float p = (float)pos[b * 2048 + s];
  float inv = exp2f(-(float)i * 0.4152410118609203f);
  float ang = p * inv;
  float sn = sinf(ang), cs = cosf(ang);
  size_t base = (((size_t)bh * 2048) + s) * 64 + 2 * i;
  float q1 = bf2f(q[base]), q2 = bf2f(q[base + 1]);
  q[base]     = f2bf(q1 * cs - q2 * sn);
  q[base + 1] = f2bf(q1 * sn + q2 * cs);
  float k1 = bf2f(k[base]), k2 = bf2f(k[base + 1]);
  k[base]     = f2bf(k1 * cs - k2 * sn);
  k[base + 1] = f2bf(k1 * sn + k2 * cs);
}

// ================= 256x256 8-phase GEMM (measured-best for qkv + w2) =================
// MODE 0: QK scatter; MODE 1: V^T scatter; MODE 5: bf16 partial out[m*1024+n]
template <int MODE>
DEV void gemm8_body(const unsigned short* __restrict__ A, int lda,
                    const unsigned short* __restrict__ B, int ldb,
                    int bm, int bn, int kbase, int nt,
                    unsigned short* __restrict__ outb,
                    unsigned short* As, unsigned short* Bs) {
  const int tid = threadIdx.x;
  const int lane = tid & 63, wid = tid >> 6;
  const int wr = wid >> 2, wc = wid & 3;
  const int m0 = bm * 256, n0 = bn * 256;

  const int r0 = tid >> 2, r1 = 128 + (tid >> 2), cc = tid & 3;
  const int sc0 = (cc ^ ((r0 >> 1) & 3)) * 8;
  const int sc1 = (cc ^ ((r1 >> 1) & 3)) * 8;
  const size_t arow0 = (size_t)(m0 + r0) * lda, arow1 = (size_t)(m0 + r1) * lda;
  const size_t brow0 = (size_t)(n0 + r0) * ldb, brow1 = (size_t)(n0 + r1) * ldb;
  const int du0 = tid * 8, du1 = (512 + tid) * 8;

  auto stA = [&](int t, int kh) {
    unsigned short* d = As + ((((t & 1) << 1) | kh) * 8192);
    const unsigned short* s = A + kbase + t * 64 + kh * 32;
    gload_lds16(s + arow0 + sc0, d + du0);
    gload_lds16(s + arow1 + sc1, d + du1);
  };
  auto stB = [&](int t, int kh) {
    unsigned short* d = Bs + ((((t & 1) << 1) | kh) * 8192);
    const unsigned short* s = B + kbase + t * 64 + kh * 32;
    gload_lds16(s + brow0 + sc0, d + du0);
    gload_lds16(s + brow1 + sc1, d + du1);
  };

  const int fcol = ((lane >> 4) ^ ((lane >> 1) & 3)) * 8;
  const int frow = lane & 15;
  const int abase = (wr * 128 + frow) * 32 + fcol;
  const int bbase = (wc * 64 + frow) * 32 + fcol;

  f32x4 acc[8][4] = {};
  bf16x8 a[4], b[4];

#define LOADA(buf, ks, mh) { const unsigned short* p_ = As + (((buf) << 1) | (ks)) * 8192 + abase + (mh) * 2048; \
  a[0] = *(const bf16x8*)(p_); a[1] = *(const bf16x8*)(p_ + 512); \
  a[2] = *(const bf16x8*)(p_ + 1024); a[3] = *(const bf16x8*)(p_ + 1536); }
#define LOADB(buf, ks) { const unsigned short* p_ = Bs + (((buf) << 1) | (ks)) * 8192 + bbase; \
  b[0] = *(const bf16x8*)(p_); b[1] = *(const bf16x8*)(p_ + 512); \
  b[2] = *(const bf16x8*)(p_ + 1024); b[3] = *(const bf16x8*)(p_ + 1536); }
#define MFMAQ(mh) { _Pragma("unroll") for (int fi = 0; fi < 4; ++fi) \
  _Pragma("unroll") for (int j = 0; j < 4; ++j) \
    acc[(mh) * 4 + fi][j] = mfma16(a[fi], b[j], acc[(mh) * 4 + fi][j]); }
#define LGK0() { asm volatile("s_waitcnt lgkmcnt(0)" ::: "memory"); }

  stA(0, 0); stB(0, 0); stA(0, 1); stB(0, 1);
  stA(1, 0); stB(1, 0);
  asm volatile("s_waitcnt vmcnt(4)" ::: "memory");
  __builtin_amdgcn_s_barrier();

  for (int t = 0; t < nt; ++t) {
    const int buf = t & 1;
    LOADA(buf, 0, 0); LOADB(buf, 0);
    if (t + 1 < nt) stA(t + 1, 1);
    __builtin_amdgcn_s_barrier();
    LGK0();
    __builtin_amdgcn_s_setprio(1); MFMAQ(0); __builtin_amdgcn_s_setprio(0);
    __builtin_amdgcn_s_barrier();
    LOADA(buf, 0, 1);
    if (t + 1 < nt) stB(t + 1, 1);
    __builtin_amdgcn_s_barrier();
    LGK0();
    __builtin_amdgcn_s_setprio(1); MFMAQ(1); __builtin_amdgcn_s_setprio(0);
    __builtin_amdgcn_s_barrier();
    LOADA(buf, 1, 0); LOADB(buf, 1);
    if (t + 2 < nt) stA(t + 2, 0);
    __builtin_amdgcn_s_barrier();
    LGK0();
    __builtin_amdgcn_s_setprio(1); MFMAQ(0); __builtin_amdgcn_s_setprio(0);
    __builtin_amdgcn_s_barrier();
    LOADA(buf, 1, 1);
    if (t + 2 < nt) stB(t + 2, 0);
    __builtin_amdgcn_s_barrier();
    LGK0();
    __builtin_amdgcn_s_setprio(1); MFMAQ(1); __builtin_amdgcn_s_setprio(0);
    if (t + 1 < nt) {
      if (t + 2 < nt) { asm volatile("s_waitcnt vmcnt(4)" ::: "memory"); }
      else            { asm volatile("s_waitcnt vmcnt(0)" ::: "memory"); }
      __builtin_amdgcn_s_barrier();
    }
  }
#undef LOADA
#undef LOADB
#undef MFMAQ
#undef LGK0

#pragma unroll
  for (int i = 0; i < 8; ++i)
#pragma unroll
    for (int j = 0; j < 4; ++j)
#pragma unroll
      for (int r = 0; r < 4; ++r) {
        int m = m0 + wr * 128 + i * 16 + ((lane >> 4) << 2) + r;
        int n = n0 + wc * 64 + j * 16 + (lane & 15);
        float v = acc[i][j][r];
        if (MODE == 0) {
          unsigned short* dst = outb + ((n >= 1024) ? 4194304 : 0);
          int nn = n & 1023;
          int bb = m >> 11, s = m & 2047, hh = nn >> 6, dd = nn & 63;
          dst[(((size_t)bb * 16 + hh) * 2048 + s) * 64 + dd] = f2bf(v);
        } else if (MODE == 1) {
          int hh = m >> 6, dd = m & 63, bb = n >> 11, s = n & 2047;
          outb[(((size_t)bb * 16 + hh) * 64 + dd) * 2048 + s] = f2bf(v);
        } else {
          outb[(size_t)m * 1024 + n] = f2bf(v);
        }
      }
}

DEV void swz_map(int bid, int nwg, int MT, int& bm, int& bn) {
  int cpx = nwg >> 3;
  int sw = (bid & 7) * cpx + (bid >> 3);
  bm = sw % MT;
  bn = sw / MT;
}

template <int MODE>
__global__ __launch_bounds__(512, 2) void gemm8_k(const unsigned short* __restrict__ A, int lda,
                                                  const unsigned short* __restrict__ B, int ldb,
                                                  int MT, int kz, int nt,
                                                  unsigned short* __restrict__ outb) {
  __shared__ __align__(16) unsigned short lds[65536];
  int bm, bn;
  swz_map(blockIdx.x, gridDim.x, MT, bm, bn);
  int kb = kz * blockIdx.y;
  unsigned short* ob = outb;
  if (MODE == 5) ob += (size_t)blockIdx.y * 4194304;
  gemm8_body<MODE>(A, lda, B, ldb, bm, bn, kb, nt, ob, lds, lds + 32768);
}

__global__ __launch_bounds__(512, 2) void gemm8_qkv(const unsigned short* __restrict__ xn,
                                                    const unsigned short* __restrict__ wqk,
                                                    const unsigned short* __restrict__ wv,
                                                    unsigned short* __restrict__ qk_out,
                                                    unsigned short* __restrict__ vt_out) {
  __shared__ __align__(16) unsigned short lds[65536];
  int bid = blockIdx.x;
  if (bid < 128) {
    int bm, bn;
    swz_map(bid, 128, 16, bm, bn);
    gemm8_body<0>(xn, 1024, wqk, 1024, bm, bn, 0, 16, qk_out, lds, lds + 32768);
  } else {
    bid -= 128;
    int bm, bn;
    swz_map(bid, 64, 4, bm, bn);
    gemm8_body<1>(wv, 1024, xn, 1024, bm, bn, 0, 16, vt_out, lds, lds + 32768);
  }
}

// ---------------- 128x128 2-phase GEMM, fp32 out = resid + acc (wo path) ----------------
template <int K>
__global__ __launch_bounds__(256) void gemm_res(const unsigned short* __restrict__ A,
                                                const unsigned short* __restrict__ Bw,
                                                float* __restrict__ outf,
                                                const float* __restrict__ resid) {
  __shared__ __align__(16) unsigned short As[128 * 64];
  __shared__ __align__(16) unsigned short Bs[128 * 64];
  const int N = 1024;
  const int tid = threadIdx.x;
  const int wid = tid >> 6, lane = tid & 63;
  const int wr = wid >> 1, wc = wid & 1;
  const int m0 = blockIdx.x * 128, n0 = blockIdx.y * 128;
  const int sw = (lane & 7) * 8;
  f32x4 acc[4][4] = {};

  for (int k0 = 0; k0 < K; k0 += 64) {
    __syncthreads();
#pragma unroll
    for (int it = 0; it < 4; ++it) {
      int c = wid * 4 + it;
      int row = c * 8 + (lane >> 3);
      int col = ((lane & 7) ^ (row & 7)) * 8;
      gload_lds16(A + (size_t)(m0 + row) * K + k0 + col, As + c * 512);
      gload_lds16(Bw + (size_t)(n0 + row) * K + k0 + col, Bs + c * 512);
    }
    asm volatile("s_waitcnt vmcnt(0)" ::: "memory");
    __syncthreads();
#pragma unroll
    for (int kk = 0; kk < 2; ++kk) {
      const int kof = (kk * 32 + (lane >> 4) * 8) ^ sw;
      bf16x8 af[4], bfr[4];
#pragma unroll
      for (int i = 0; i < 4; ++i) {
        af[i]  = *(const bf16x8*)(As + (wr * 64 + i * 16 + (lane & 15)) * 64 + kof);
        bfr[i] = *(const bf16x8*)(Bs + (wc * 64 + i * 16 + (lane & 15)) * 64 + kof);
      }
#pragma unroll
      for (int i = 0; i < 4; ++i)
#pragma unroll
        for (int j = 0; j < 4; ++j) acc[i][j] = mfma16(af[i], bfr[j], acc[i][j]);
    }
  }
  const int rb = m0 + wr * 64 + ((lane >> 4) * 4);
  const int cb = n0 + wc * 64 + (lane & 15);
#pragma unroll
  for (int i = 0; i < 4; ++i)
#pragma unroll
    for (int r = 0; r < 4; ++r) {
      int m = rb + i * 16 + r;
#pragma unroll
      for (int j = 0; j < 4; ++j) {
        size_t idx = (size_t)m * N + cb + j * 16;
        outf[idx] = resid[idx] + acc[i][j][r];
      }
    }
}

// ---------------- 128x128 2-phase fused SwiGLU (measured-best for w1+w3) ----------------
// A = xn [4096][1024], B = w13 interleaved [8192][1024]; even n=g, odd n=u
// out hb[m*4096 + n/2] = silu(g)*u
__global__ __launch_bounds__(256) void swiglu2_k(const unsigned short* __restrict__ A,
                                                 const unsigned short* __restrict__ B,
                                                 unsigned short* __restrict__ outb) {
  __shared__ __align__(16) unsigned short As[128 * 64];
  __shared__ __align__(16) unsigned short Bs[128 * 64];
  const int K = 1024;
  const int tid = threadIdx.x;
  const int wid = tid >> 6, lane = tid & 63;
  const int wr = wid >> 1, wc = wid & 1;
  const int m0 = blockIdx.x * 128, n0 = blockIdx.y * 128;
  const int sw = (lane & 7) * 8;
  f32x4 acc[4][4] = {};

  for (int k0 = 0; k0 < K; k0 += 64) {
    __syncthreads();
#pragma unroll
    for (int it = 0; it < 4; ++it) {
      int c = wid * 4 + it;
      int row = c * 8 + (lane >> 3);
      int col = ((lane & 7) ^ (row & 7)) * 8;
      gload_lds16(A + (size_t)(m0 + row) * K + k0 + col, As + c * 512);
      gload_lds16(B + (size_t)(n0 + row) * K + k0 + col, Bs + c * 512);
    }
    asm volatile("s_waitcnt vmcnt(0)" ::: "memory");
    __syncthreads();
#pragma unroll
    for (int kk = 0; kk < 2; ++kk) {
      const int kof = (kk * 32 + (lane >> 4) * 8) ^ sw;
      bf16x8 af[4], bfr[4];
#pragma unroll
      for (int i = 0; i < 4; ++i) {
        af[i]  = *(const bf16x8*)(As + (wr * 64 + i * 16 + (lane & 15)) * 64 + kof);
        bfr[i] = *(const bf16x8*)(Bs + (wc * 64 + i * 16 + (lane & 15)) * 64 + kof);
      }
#pragma unroll
      for (int i = 0; i < 4; ++i)
#pragma unroll
        for (int j = 0; j < 4; ++j) acc[i][j] = mfma16(af[i], bfr[j], acc[i][j]);
    }
  }
  const int rb = m0 + wr * 64 + ((lane >> 4) * 4);
  const int cb = n0 + wc * 64 + (lane & 15);
#pragma unroll
  for (int i = 0; i < 4; ++i)
#pragma unroll
    for (int r = 0; r < 4; ++r) {
      int m = rb + i * 16 + r;
#pragma unroll
      for (int j = 0; j < 4; ++j) {
        int n = cb + j * 16;
        float v = acc[i][j][r];
        float other = __shfl_xor(v, 1);
        if (!(lane & 1)) {
          float hv = v / (1.0f + __expf(-v)) * other;
          outb[(size_t)m * 4096 + (n >> 1)] = f2bf(hv);
        }
      }
    }
}

// ---------------- w2 split-K reduce (bf16 partials) ----------------
__global__ __launch_bounds__(256) void reduce_k(float* __restrict__ out,
                                                const unsigned short* __restrict__ partb) {
  int i = (blockIdx.x * 256 + threadIdx.x) * 4;
  float4 o = *(const float4*)(out + i);
#pragma unroll
  for (int s = 0; s < 4; ++s) {
    uint2 w = *(const uint2*)(partb + (size_t)s * 4194304 + i);
    o.x += bf2f((unsigned short)(w.x & 0xffff));
    o.y += bf2f((unsigned short)(w.x >> 16));
    o.z += bf2f((unsigned short)(w.y & 0xffff));
    o.w += bf2f((unsigned short)(w.y >> 16));
  }
  *(float4*)(out + i) = o;
}

// ---------------- Flash attention: swapped-QK 16x16, dbuf, in-reg softmax ----------------
__global__ __launch_bounds__(256) void attn_k(const unsigned short* __restrict__ q,
                                              const unsigned short* __restrict__ k,
                                              const unsigned short* __restrict__ vt,
                                              unsigned short* __restrict__ ctx) {
  __shared__ __align__(16) unsigned short Ks[2][4096];
  __shared__ __align__(16) unsigned short Vs[2][4096];
  __shared__ __align__(16) unsigned short Ps[4][16 * 72];
  const int bid = blockIdx.x;                       // 1024 blocks
  const int bh = (bid & 7) * 4 + ((bid >> 3) & 3);  // XCD-pinned: 4 heads/XCD
  const int qt = 31 - (bid >> 5);                   // longest first
  const int tid = threadIdx.x, wid = tid >> 6, lane = tid & 63;
  const size_t bhS = (size_t)bh * 2048;
  const size_t bhD = (size_t)bh * 64 * 2048;
  const int b = bh >> 4, hh = bh & 15;
  const int sw = (lane & 7) * 8;
  const int h4 = lane >> 4, l15 = lane & 15;
  const float SC2 = 0.18033688011112042f;  // 0.125 * log2(e)

  const int c0 = wid * 2, c1 = wid * 2 + 1;
  const int row0 = c0 * 8 + (lane >> 3), row1 = c1 * 8 + (lane >> 3);
  const int col0 = ((lane & 7) ^ (row0 & 7)) * 8;
  const int col1 = ((lane & 7) ^ (row1 & 7)) * 8;

  auto stage = [&](int kt, int buf) {
    gload_lds16(k + (bhS + kt * 64 + row0) * 64 + col0, &Ks[buf][c0 * 512]);
    gload_lds16(k + (bhS + kt * 64 + row1) * 64 + col1, &Ks[buf][c1 * 512]);
    gload_lds16(vt + bhD + (size_t)row0 * 2048 + kt * 64 + col0, &Vs[buf][c0 * 512]);
    gload_lds16(vt + bhD + (size_t)row1 * 2048 + kt * 64 + col1, &Vs[buf][c1 * 512]);
  };

  const int q0 = qt * 64;
  bf16x8 qf[2];
  {
    const unsigned short* qp = q + (bhS + q0 + wid * 16 + l15) * 64 + h4 * 8;
    qf[0] = *(const bf16x8*)qp;
    qf[1] = *(const bf16x8*)(qp + 32);
#pragma unroll
    for (int jj = 0; jj < 8; ++jj) {
      qf[0][jj] = (__bf16)((float)qf[0][jj] * SC2);
      qf[1][jj] = (__bf16)((float)qf[1][jj] * SC2);
    }
  }
  float mrow = -1e30f, lrow = 0.0f;
  f32x4 o[4] = {};
  const int qg = q0 + wid * 16 + l15;          // lane's own q (S column)
  const int rowb = q0 + wid * 16 + (h4 << 2);  // output q rows

  stage(0, 0);
  if (qt > 0) { stage(1, 1); asm volatile("s_waitcnt vmcnt(4)" ::: "memory"); }
  else        {              asm volatile("s_waitcnt vmcnt(0)" ::: "memory"); }
  __builtin_amdgcn_s_barrier();

  for (int kt = 0; kt <= qt; ++kt) {
    const int cur = kt & 1;
    float s[16];
#pragma unroll
    for (int nt = 0; nt < 4; ++nt) {
      f32x4 z = {};
#pragma unroll
      for (int ks = 0; ks < 2; ++ks) {
        int kof = (ks * 32 + h4 * 8) ^ sw;
        bf16x8 kf = *(const bf16x8*)(&Ks[cur][(nt * 16 + l15) * 64 + kof]);
        z = mfma16(kf, qf[ks], z);
      }
      s[nt * 4 + 0] = z[0]; s[nt * 4 + 1] = z[1];
      s[nt * 4 + 2] = z[2]; s[nt * 4 + 3] = z[3];
    }
    if (kt == qt) {
#pragma unroll
      for (int nt = 0; nt < 4; ++nt)
#pragma unroll
        for (int r = 0; r < 4; ++r) {
          int key = q0 + nt * 16 + (h4 << 2) + r;
          if (key > qg) s[nt * 4 + r] = -3e38f;
        }
    }
    float pmax = s[0];
#pragma unroll
    for (int i = 1; i < 16; ++i) pmax = fmaxf(pmax, s[i]);
    pmax = fmaxf(pmax, __shfl_xor(pmax, 16));
    pmax = fmaxf(pmax, __shfl_xor(pmax, 32));
    if (!__all(pmax <= mrow + 11.5f)) {
      float mnew = fmaxf(mrow, pmax);
      float dl = mrow - mnew;
      mrow = mnew;
      lrow *= fexp2(dl);
#pragma unroll
      for (int r = 0; r < 4; ++r) {
        float ar = fexp2(__shfl(dl, (h4 << 2) + r, 16));
#pragma unroll
        for (int d = 0; d < 4; ++d) o[d][r] *= ar;
      }
    }
    float sum = 0.0f;
#pragma unroll
    for (int i = 0; i < 16; ++i) { s[i] = fexp2(s[i] - mrow); sum += s[i]; }
    lrow += sum;
    {
      unsigned short* pr = &Ps[wid][l15 * 72 + (h4 << 2)];
#pragma unroll
      for (int nt = 0; nt < 4; ++nt) {
        uint2 w;
        w.x = pkbf(s[4 * nt], s[4 * nt + 1]);
        w.y = pkbf(s[4 * nt + 2], s[4 * nt + 3]);
        *(uint2*)(pr + nt * 16) = w;
      }
    }
#pragma unroll
    for (int ks = 0; ks < 2; ++ks) {
      bf16x8 pf = *(const bf16x8*)(&Ps[wid][l15 * 72 + ks * 32 + (h4 << 3)]);
      int kof = (ks * 32 + h4 * 8) ^ sw;
#pragma unroll
      for (int d = 0; d < 4; ++d) {
        bf16x8 vf = *(const bf16x8*)(&Vs[cur][(d * 16 + l15) * 64 + kof]);
        o[d] = mfma16(pf, vf, o[d]);
      }
    }
    __builtin_amdgcn_s_barrier();
    if (kt + 2 <= qt) {
      stage(kt + 2, cur);
      asm volatile("s_waitcnt vmcnt(4)" ::: "memory");
    } else if (kt + 1 <= qt) {
      asm volatile("s_waitcnt vmcnt(0)" ::: "memory");
    }
    __builtin_amdgcn_s_barrier();
  }
  lrow += __shfl_xor(lrow, 16);
  lrow += __shfl_xor(lrow, 32);
  float inv = 1.0f / lrow;
#pragma unroll
  for (int r = 0; r < 4; ++r) {
    float invr = __shfl(inv, (h4 << 2) + r, 16);
#pragma unroll
    for (int d = 0; d < 4; ++d)
      ctx[((size_t)b * 2048 + (rowb + r)) * 1024 + hh * 64 + d * 16 + l15] = f2bf(o[d][r] * invr);
  }
}

extern "C" void kernel_launch(void* const* d_in, const int* in_sizes, int n_in,
                              void* d_out, int out_size, void* d_ws, size_t ws_size,
                              hipStream_t stream) {
  (void)in_sizes; (void)n_in; (void)out_size; (void)ws_size;
  const float* in_f = (const float*)d_in[0];
  const int* pos    = (const int*)d_in[1];
  const float* q_w  = (const float*)d_in[2];
  const float* k_w  = (const float*)d_in[3];
  const float* v_w  = (const float*)d_in[4];
  const float* o_w  = (const float*)d_in[5];
  const float* ln1  = (const float*)d_in[6];
  const float* ln2  = (const float*)d_in[7];
  const float* w1   = (const float*)d_in[8];
  const float* w2   = (const float*)d_in[9];
  const float* w3   = (const float*)d_in[10];
  float* out = (float*)d_out;

  unsigned short* ws = (unsigned short*)d_ws;
  unsigned short* wb   = ws;
  unsigned short* wqkb = wb;                // 2M
  unsigned short* wvb  = wb + 2097152;      // 1M
  unsigned short* wob  = wb + 3145728;      // 1M
  unsigned short* w2b  = wb + 4194304;      // 4M
  unsigned short* w13b = wb + 8388608;      // 8M (row-interleaved w1/w3)
  unsigned short* xn   = ws + 16777216;
  unsigned short* qb   = ws + 20971520;
  unsigned short* kb   = ws + 25165824;     // must be qb + 4194304
  unsigned short* vb   = ws + 29360128;     // V^T [bh][64][2048]
  unsigned short* cx   = ws + 33554432;
  unsigned short* partb = ws + 20971520;    // 16M u16 bf16 partials, aliases qb..cx (dead by w2)
  unsigned short* hb   = ws + 54525952;

  CvtArgs ca;
  ca.src[0] = q_w; ca.src[1] = k_w; ca.src[2] = v_w; ca.src[3] = o_w;
  ca.src[4] = w2;  ca.src[5] = w1;  ca.src[6] = w3;
  ca.cum[0] = 0;        ca.cum[1] = 1048576;  ca.cum[2] = 2097152;  ca.cum[3] = 3145728;
  ca.cum[4] = 4194304;  ca.cum[5] = 8388608;  ca.cum[6] = 12582912; ca.cum[7] = 16777216;
  cvt_all<<<16384, 256, 0, stream>>>(ca, wb);

  rmsnorm_k<<<4096, 256, 0, stream>>>(in_f, ln1, xn);

  gemm8_qkv<<<192, 512, 0, stream>>>(xn, wqkb, wvb, qb, vb);

  rope2_k<<<8192, 256, 0, stream>>>(qb, kb, pos);

  attn_k<<<1024, 256, 0, stream>>>(qb, kb, vb, cx);

  gemm_res<1024><<<dim3(32, 8), 256, 0, stream>>>(cx, wob, out, in_f);

  rmsnorm_k<<<4096, 256, 0, stream>>>(out, ln2, xn);

  // fused w1+w3 SwiGLU (2-phase, measured-best): M=4096, N=8192 -> hb bf16
  swiglu2_k<<<dim3(32, 64), 256, 0, stream>>>(xn, w13b, hb);

  // w2 split-K=4 (8-phase, measured-best), bf16 partials
  gemm8_k<5><<<dim3(64, 4), 512, 0, stream>>>(hb, 4096, w2b, 4096, 16, 1024, 16, partb);

  reduce_k<<<4096, 256, 0, stream>>>(out, partb);
}

// Round 16
// 285.083 us; speedup vs baseline: 1.0034x; 1.0034x over previous
//
#include <hip/hip_runtime.h>
#include <hip/hip_bf16.h>

typedef __attribute__((ext_vector_type(8))) __bf16 bf16x8;
typedef __attribute__((ext_vector_type(4))) float f32x4;

#define DEV static __device__ __forceinline__

DEV unsigned short f2bf(float f) {
  __bf16 h = (__bf16)f;
  union { __bf16 h; unsigned short u; } v; v.h = h;
  return v.u;
}
DEV float bf2f(unsigned short h) {
  union { unsigned int u; float f; } v; v.u = ((unsigned int)h) << 16;
  return v.f;
}
DEV unsigned pkbf(float lo, float hi) {
  union { __bf16 h[2]; unsigned u; } v;
  v.h[0] = (__bf16)lo; v.h[1] = (__bf16)hi;
  return v.u;
}
DEV f32x4 mfma16(bf16x8 a, bf16x8 b, f32x4 c) {
  return __builtin_amdgcn_mfma_f32_16x16x32_bf16(a, b, c, 0, 0, 0);
}
DEV void gload_lds16(const void* g, void* l) {
  __builtin_amdgcn_global_load_lds((__attribute__((address_space(1))) void*)g,
                                   (__attribute__((address_space(3))) void*)l,
                                   16, 0, 0);
}
DEV float fexp2(float x) { return exp2f(x); }

// ---------------- fused f32 -> bf16 convert of all 7 weights ----------------
// regions: 0 q_w 1 k_w 2 v_w 3 o_w 4 w2 (linear) | 5 w1, 6 w3 (row-interleaved into w13)
struct CvtArgs { const float* src[7]; int cum[8]; };
__global__ __launch_bounds__(256) void cvt_all(CvtArgs a, unsigned short* __restrict__ dst) {
  int i = (blockIdx.x * 256 + threadIdx.x) * 4;
  if (i >= a.cum[7]) return;
  int w = 0;
#pragma unroll 7
  for (int t = 0; t < 7; ++t) if (i >= a.cum[t + 1]) w = t + 1;
  int local = i - a.cum[w];
  int di;
  if (w == 5)      di = 8388608 + ((local >> 10) << 11) + (local & 1023);          // w1 -> row 2f
  else if (w == 6) di = 8388608 + ((local >> 10) << 11) + 1024 + (local & 1023);   // w3 -> row 2f+1
  else             di = i;
  float4 v = *(const float4*)(a.src[w] + local);
  dst[di + 0] = f2bf(v.x);
  dst[di + 1] = f2bf(v.y);
  dst[di + 2] = f2bf(v.z);
  dst[di + 3] = f2bf(v.w);
}

// ---------------- RMSNorm: fp32 in -> bf16 out (D=1024) ----------------
__global__ __launch_bounds__(256) void rmsnorm_k(const float* __restrict__ x,
                                                 const float* __restrict__ w,
                                                 unsigned short* __restrict__ out) {
  int row = blockIdx.x;
  int tid = threadIdx.x;
  const float* xr = x + (size_t)row * 1024;
  float4 v = *(const float4*)(xr + tid * 4);
  float ss = v.x * v.x + v.y * v.y + v.z * v.z + v.w * v.w;
#pragma unroll
  for (int m = 32; m >= 1; m >>= 1) ss += __shfl_xor(ss, m);
  __shared__ float red[4];
  int wid = tid >> 6;
  if ((tid & 63) == 0) red[wid] = ss;
  __syncthreads();
  float tot = red[0] + red[1] + red[2] + red[3];
  float rs = rsqrtf(tot * (1.0f / 1024.0f) + 1e-5f);
  float4 wv = *(const float4*)(w + tid * 4);
  unsigned short* o = out + (size_t)row * 1024 + tid * 4;
  o[0] = f2bf(v.x * rs * wv.x);
  o[1] = f2bf(v.y * rs * wv.y);
  o[2] = f2bf(v.z * rs * wv.z);
  o[3] = f2bf(v.w * rs * wv.w);
}

// ---------------- RoPE in-place: one thread rotates q AND k ----------------
__global__ __launch_bounds__(256) void rope2_k(unsigned short* __restrict__ q,
                                               unsigned short* __restrict__ k,
                                               const int* __restrict__ pos) {
  int idx = blockIdx.x * 256 + threadIdx.x;  // 2,097,152 threads
  int i = idx & 31;
  int s = (idx >> 5) & 2047;
  int bh = idx >> 16;
  int b = bh >> 4;
  float p = (float)pos[b * 2048 + s];
  float inv = exp2f(-(float)i * 0.4152410118609203f);
  float ang = p * inv;
  float sn = sinf(ang), cs = cosf(ang);
  size_t base = (((size_t)bh * 2048) + s) * 64 + 2 * i;
  float q1 = bf2f(q[base]), q2 = bf2f(q[base + 1]);
  q[base]     = f2bf(q1 * cs - q2 * sn);
  q[base + 1] = f2bf(q1 * sn + q2 * cs);
  float k1 = bf2f(k[base]), k2 = bf2f(k[base + 1]);
  k[base]     = f2bf(k1 * cs - k2 * sn);
  k[base + 1] = f2bf(k1 * sn + k2 * cs);
}

// ================= 256x256 8-phase GEMM (measured-best for qkv + w2) =================
// MODE 0: QK scatter; MODE 1: V^T scatter; MODE 5: bf16 partial out[m*1024+n]
template <int MODE>
DEV void gemm8_body(const unsigned short* __restrict__ A, int lda,
                    const unsigned short* __restrict__ B, int ldb,
                    int bm, int bn, int kbase, int nt,
                    unsigned short* __restrict__ outb,
                    unsigned short* As, unsigned short* Bs) {
  const int tid = threadIdx.x;
  const int lane = tid & 63, wid = tid >> 6;
  const int wr = wid >> 2, wc = wid & 3;
  const int m0 = bm * 256, n0 = bn * 256;

  const int r0 = tid >> 2, r1 = 128 + (tid >> 2), cc = tid & 3;
  const int sc0 = (cc ^ ((r0 >> 1) & 3)) * 8;
  const int sc1 = (cc ^ ((r1 >> 1) & 3)) * 8;
  const size_t arow0 = (size_t)(m0 + r0) * lda, arow1 = (size_t)(m0 + r1) * lda;
  const size_t brow0 = (size_t)(n0 + r0) * ldb, brow1 = (size_t)(n0 + r1) * ldb;
  const int du0 = tid * 8, du1 = (512 + tid) * 8;

  auto stA = [&](int t, int kh) {
    unsigned short* d = As + ((((t & 1) << 1) | kh) * 8192);
    const unsigned short* s = A + kbase + t * 64 + kh * 32;
    gload_lds16(s + arow0 + sc0, d + du0);
    gload_lds16(s + arow1 + sc1, d + du1);
  };
  auto stB = [&](int t, int kh) {
    unsigned short* d = Bs + ((((t & 1) << 1) | kh) * 8192);
    const unsigned short* s = B + kbase + t * 64 + kh * 32;
    gload_lds16(s + brow0 + sc0, d + du0);
    gload_lds16(s + brow1 + sc1, d + du1);
  };

  const int fcol = ((lane >> 4) ^ ((lane >> 1) & 3)) * 8;
  const int frow = lane & 15;
  const int abase = (wr * 128 + frow) * 32 + fcol;
  const int bbase = (wc * 64 + frow) * 32 + fcol;

  f32x4 acc[8][4] = {};
  bf16x8 a[4], b[4];

#define LOADA(buf, ks, mh) { const unsigned short* p_ = As + (((buf) << 1) | (ks)) * 8192 + abase + (mh) * 2048; \
  a[0] = *(const bf16x8*)(p_); a[1] = *(const bf16x8*)(p_ + 512); \
  a[2] = *(const bf16x8*)(p_ + 1024); a[3] = *(const bf16x8*)(p_ + 1536); }
#define LOADB(buf, ks) { const unsigned short* p_ = Bs + (((buf) << 1) | (ks)) * 8192 + bbase; \
  b[0] = *(const bf16x8*)(p_); b[1] = *(const bf16x8*)(p_ + 512); \
  b[2] = *(const bf16x8*)(p_ + 1024); b[3] = *(const bf16x8*)(p_ + 1536); }
#define MFMAQ(mh) { _Pragma("unroll") for (int fi = 0; fi < 4; ++fi) \
  _Pragma("unroll") for (int j = 0; j < 4; ++j) \
    acc[(mh) * 4 + fi][j] = mfma16(a[fi], b[j], acc[(mh) * 4 + fi][j]); }
#define LGK0() { asm volatile("s_waitcnt lgkmcnt(0)" ::: "memory"); }

  stA(0, 0); stB(0, 0); stA(0, 1); stB(0, 1);
  stA(1, 0); stB(1, 0);
  asm volatile("s_waitcnt vmcnt(4)" ::: "memory");
  __builtin_amdgcn_s_barrier();

  for (int t = 0; t < nt; ++t) {
    const int buf = t & 1;
    LOADA(buf, 0, 0); LOADB(buf, 0);
    if (t + 1 < nt) stA(t + 1, 1);
    __builtin_amdgcn_s_barrier();
    LGK0();
    __builtin_amdgcn_s_setprio(1); MFMAQ(0); __builtin_amdgcn_s_setprio(0);
    __builtin_amdgcn_s_barrier();
    LOADA(buf, 0, 1);
    if (t + 1 < nt) stB(t + 1, 1);
    __builtin_amdgcn_s_barrier();
    LGK0();
    __builtin_amdgcn_s_setprio(1); MFMAQ(1); __builtin_amdgcn_s_setprio(0);
    __builtin_amdgcn_s_barrier();
    LOADA(buf, 1, 0); LOADB(buf, 1);
    if (t + 2 < nt) stA(t + 2, 0);
    __builtin_amdgcn_s_barrier();
    LGK0();
    __builtin_amdgcn_s_setprio(1); MFMAQ(0); __builtin_amdgcn_s_setprio(0);
    __builtin_amdgcn_s_barrier();
    LOADA(buf, 1, 1);
    if (t + 2 < nt) stB(t + 2, 0);
    __builtin_amdgcn_s_barrier();
    LGK0();
    __builtin_amdgcn_s_setprio(1); MFMAQ(1); __builtin_amdgcn_s_setprio(0);
    if (t + 1 < nt) {
      if (t + 2 < nt) { asm volatile("s_waitcnt vmcnt(4)" ::: "memory"); }
      else            { asm volatile("s_waitcnt vmcnt(0)" ::: "memory"); }
      __builtin_amdgcn_s_barrier();
    }
  }
#undef LOADA
#undef LOADB
#undef MFMAQ
#undef LGK0

#pragma unroll
  for (int i = 0; i < 8; ++i)
#pragma unroll
    for (int j = 0; j < 4; ++j)
#pragma unroll
      for (int r = 0; r < 4; ++r) {
        int m = m0 + wr * 128 + i * 16 + ((lane >> 4) << 2) + r;
        int n = n0 + wc * 64 + j * 16 + (lane & 15);
        float v = acc[i][j][r];
        if (MODE == 0) {
          unsigned short* dst = outb + ((n >= 1024) ? 4194304 : 0);
          int nn = n & 1023;
          int bb = m >> 11, s = m & 2047, hh = nn >> 6, dd = nn & 63;
          dst[(((size_t)bb * 16 + hh) * 2048 + s) * 64 + dd] = f2bf(v);
        } else if (MODE == 1) {
          int hh = m >> 6, dd = m & 63, bb = n >> 11, s = n & 2047;
          outb[(((size_t)bb * 16 + hh) * 64 + dd) * 2048 + s] = f2bf(v);
        } else {
          outb[(size_t)m * 1024 + n] = f2bf(v);
        }
      }
}

DEV void swz_map(int bid, int nwg, int MT, int& bm, int& bn) {
  int cpx = nwg >> 3;
  int sw = (bid & 7) * cpx + (bid >> 3);
  bm = sw % MT;
  bn = sw / MT;
}

template <int MODE>
__global__ __launch_bounds__(512, 2) void gemm8_k(const unsigned short* __restrict__ A, int lda,
                                                  const unsigned short* __restrict__ B, int ldb,
                                                  int MT, int kz, int nt,
                                                  unsigned short* __restrict__ outb) {
  __shared__ __align__(16) unsigned short lds[65536];
  int bm, bn;
  swz_map(blockIdx.x, gridDim.x, MT, bm, bn);
  int kb = kz * blockIdx.y;
  unsigned short* ob = outb;
  if (MODE == 5) ob += (size_t)blockIdx.y * 4194304;
  gemm8_body<MODE>(A, lda, B, ldb, bm, bn, kb, nt, ob, lds, lds + 32768);
}

__global__ __launch_bounds__(512, 2) void gemm8_qkv(const unsigned short* __restrict__ xn,
                                                    const unsigned short* __restrict__ wqk,
                                                    const unsigned short* __restrict__ wv,
                                                    unsigned short* __restrict__ qk_out,
                                                    unsigned short* __restrict__ vt_out) {
  __shared__ __align__(16) unsigned short lds[65536];
  int bid = blockIdx.x;
  if (bid < 128) {
    int bm, bn;
    swz_map(bid, 128, 16, bm, bn);
    gemm8_body<0>(xn, 1024, wqk, 1024, bm, bn, 0, 16, qk_out, lds, lds + 32768);
  } else {
    bid -= 128;
    int bm, bn;
    swz_map(bid, 64, 4, bm, bn);
    gemm8_body<1>(wv, 1024, xn, 1024, bm, bn, 0, 16, vt_out, lds, lds + 32768);
  }
}

// ---------------- 128x128 2-phase GEMM, fp32 out = resid + acc (wo path) ----------------
template <int K>
__global__ __launch_bounds__(256) void gemm_res(const unsigned short* __restrict__ A,
                                                const unsigned short* __restrict__ Bw,
                                                float* __restrict__ outf,
                                                const float* __restrict__ resid) {
  __shared__ __align__(16) unsigned short As[128 * 64];
  __shared__ __align__(16) unsigned short Bs[128 * 64];
  const int N = 1024;
  const int tid = threadIdx.x;
  const int wid = tid >> 6, lane = tid & 63;
  const int wr = wid >> 1, wc = wid & 1;
  const int m0 = blockIdx.x * 128, n0 = blockIdx.y * 128;
  const int sw = (lane & 7) * 8;
  f32x4 acc[4][4] = {};

  for (int k0 = 0; k0 < K; k0 += 64) {
    __syncthreads();
#pragma unroll
    for (int it = 0; it < 4; ++it) {
      int c = wid * 4 + it;
      int row = c * 8 + (lane >> 3);
      int col = ((lane & 7) ^ (row & 7)) * 8;
      gload_lds16(A + (size_t)(m0 + row) * K + k0 + col, As + c * 512);
      gload_lds16(Bw + (size_t)(n0 + row) * K + k0 + col, Bs + c * 512);
    }
    asm volatile("s_waitcnt vmcnt(0)" ::: "memory");
    __syncthreads();
#pragma unroll
    for (int kk = 0; kk < 2; ++kk) {
      const int kof = (kk * 32 + (lane >> 4) * 8) ^ sw;
      bf16x8 af[4], bfr[4];
#pragma unroll
      for (int i = 0; i < 4; ++i) {
        af[i]  = *(const bf16x8*)(As + (wr * 64 + i * 16 + (lane & 15)) * 64 + kof);
        bfr[i] = *(const bf16x8*)(Bs + (wc * 64 + i * 16 + (lane & 15)) * 64 + kof);
      }
#pragma unroll
      for (int i = 0; i < 4; ++i)
#pragma unroll
        for (int j = 0; j < 4; ++j) acc[i][j] = mfma16(af[i], bfr[j], acc[i][j]);
    }
  }
  const int rb = m0 + wr * 64 + ((lane >> 4) * 4);
  const int cb = n0 + wc * 64 + (lane & 15);
#pragma unroll
  for (int i = 0; i < 4; ++i)
#pragma unroll
    for (int r = 0; r < 4; ++r) {
      int m = rb + i * 16 + r;
#pragma unroll
      for (int j = 0; j < 4; ++j) {
        size_t idx = (size_t)m * N + cb + j * 16;
        outf[idx] = resid[idx] + acc[i][j][r];
      }
    }
}

// ---------------- 128x128 2-phase fused SwiGLU (measured-best for w1+w3) ----------------
// A = xn [4096][1024], B = w13 interleaved [8192][1024]; even n=g, odd n=u
// out hb[m*4096 + n/2] = silu(g)*u
__global__ __launch_bounds__(256) void swiglu2_k(const unsigned short* __restrict__ A,
                                                 const unsigned short* __restrict__ B,
                                                 unsigned short* __restrict__ outb) {
  __shared__ __align__(16) unsigned short As[128 * 64];
  __shared__ __align__(16) unsigned short Bs[128 * 64];
  const int K = 1024;
  const int tid = threadIdx.x;
  const int wid = tid >> 6, lane = tid & 63;
  const int wr = wid >> 1, wc = wid & 1;
  const int m0 = blockIdx.x * 128, n0 = blockIdx.y * 128;
  const int sw = (lane & 7) * 8;
  f32x4 acc[4][4] = {};

  for (int k0 = 0; k0 < K; k0 += 64) {
    __syncthreads();
#pragma unroll
    for (int it = 0; it < 4; ++it) {
      int c = wid * 4 + it;
      int row = c * 8 + (lane >> 3);
      int col = ((lane & 7) ^ (row & 7)) * 8;
      gload_lds16(A + (size_t)(m0 + row) * K + k0 + col, As + c * 512);
      gload_lds16(B + (size_t)(n0 + row) * K + k0 + col, Bs + c * 512);
    }
    asm volatile("s_waitcnt vmcnt(0)" ::: "memory");
    __syncthreads();
#pragma unroll
    for (int kk = 0; kk < 2; ++kk) {
      const int kof = (kk * 32 + (lane >> 4) * 8) ^ sw;
      bf16x8 af[4], bfr[4];
#pragma unroll
      for (int i = 0; i < 4; ++i) {
        af[i]  = *(const bf16x8*)(As + (wr * 64 + i * 16 + (lane & 15)) * 64 + kof);
        bfr[i] = *(const bf16x8*)(Bs + (wc * 64 + i * 16 + (lane & 15)) * 64 + kof);
      }
#pragma unroll
      for (int i = 0; i < 4; ++i)
#pragma unroll
        for (int j = 0; j < 4; ++j) acc[i][j] = mfma16(af[i], bfr[j], acc[i][j]);
    }
  }
  const int rb = m0 + wr * 64 + ((lane >> 4) * 4);
  const int cb = n0 + wc * 64 + (lane & 15);
#pragma unroll
  for (int i = 0; i < 4; ++i)
#pragma unroll
    for (int r = 0; r < 4; ++r) {
      int m = rb + i * 16 + r;
#pragma unroll
      for (int j = 0; j < 4; ++j) {
        int n = cb + j * 16;
        float v = acc[i][j][r];
        float other = __shfl_xor(v, 1);
        if (!(lane & 1)) {
          float hv = v / (1.0f + __expf(-v)) * other;
          outb[(size_t)m * 4096 + (n >> 1)] = f2bf(hv);
        }
      }
    }
}

// ---------------- w2 split-K reduce (bf16 partials) ----------------
__global__ __launch_bounds__(256) void reduce_k(float* __restrict__ out,
                                                const unsigned short* __restrict__ partb) {
  int i = (blockIdx.x * 256 + threadIdx.x) * 4;
  float4 o = *(const float4*)(out + i);
#pragma unroll
  for (int s = 0; s < 4; ++s) {
    uint2 w = *(const uint2*)(partb + (size_t)s * 4194304 + i);
    o.x += bf2f((unsigned short)(w.x & 0xffff));
    o.y += bf2f((unsigned short)(w.x >> 16));
    o.z += bf2f((unsigned short)(w.y & 0xffff));
    o.w += bf2f((unsigned short)(w.y >> 16));
  }
  *(float4*)(out + i) = o;
}

// ---------------- Flash attention: swapped-QK 16x16, dbuf, in-reg softmax ----------------
__global__ __launch_bounds__(256) void attn_k(const unsigned short* __restrict__ q,
                                              const unsigned short* __restrict__ k,
                                              const unsigned short* __restrict__ vt,
                                              unsigned short* __restrict__ ctx) {
  __shared__ __align__(16) unsigned short Ks[2][4096];
  __shared__ __align__(16) unsigned short Vs[2][4096];
  __shared__ __align__(16) unsigned short Ps[4][16 * 72];
  const int bid = blockIdx.x;                       // 1024 blocks
  const int bh = (bid & 7) * 4 + ((bid >> 3) & 3);  // XCD-pinned: 4 heads/XCD
  const int qt = 31 - (bid >> 5);                   // longest first
  const int tid = threadIdx.x, wid = tid >> 6, lane = tid & 63;
  const size_t bhS = (size_t)bh * 2048;
  const size_t bhD = (size_t)bh * 64 * 2048;
  const int b = bh >> 4, hh = bh & 15;
  const int sw = (lane & 7) * 8;
  const int h4 = lane >> 4, l15 = lane & 15;
  const float SC2 = 0.18033688011112042f;  // 0.125 * log2(e)

  const int c0 = wid * 2, c1 = wid * 2 + 1;
  const int row0 = c0 * 8 + (lane >> 3), row1 = c1 * 8 + (lane >> 3);
  const int col0 = ((lane & 7) ^ (row0 & 7)) * 8;
  const int col1 = ((lane & 7) ^ (row1 & 7)) * 8;

  auto stage = [&](int kt, int buf) {
    gload_lds16(k + (bhS + kt * 64 + row0) * 64 + col0, &Ks[buf][c0 * 512]);
    gload_lds16(k + (bhS + kt * 64 + row1) * 64 + col1, &Ks[buf][c1 * 512]);
    gload_lds16(vt + bhD + (size_t)row0 * 2048 + kt * 64 + col0, &Vs[buf][c0 * 512]);
    gload_lds16(vt + bhD + (size_t)row1 * 2048 + kt * 64 + col1, &Vs[buf][c1 * 512]);
  };

  const int q0 = qt * 64;
  bf16x8 qf[2];
  {
    const unsigned short* qp = q + (bhS + q0 + wid * 16 + l15) * 64 + h4 * 8;
    qf[0] = *(const bf16x8*)qp;
    qf[1] = *(const bf16x8*)(qp + 32);
#pragma unroll
    for (int jj = 0; jj < 8; ++jj) {
      qf[0][jj] = (__bf16)((float)qf[0][jj] * SC2);
      qf[1][jj] = (__bf16)((float)qf[1][jj] * SC2);
    }
  }
  float mrow = -1e30f, lrow = 0.0f;
  f32x4 o[4] = {};
  const int qg = q0 + wid * 16 + l15;          // lane's own q (S column)
  const int rowb = q0 + wid * 16 + (h4 << 2);  // output q rows

  stage(0, 0);
  if (qt > 0) { stage(1, 1); asm volatile("s_waitcnt vmcnt(4)" ::: "memory"); }
  else        {              asm volatile("s_waitcnt vmcnt(0)" ::: "memory"); }
  __builtin_amdgcn_s_barrier();

  for (int kt = 0; kt <= qt; ++kt) {
    const int cur = kt & 1;
    float s[16];
#pragma unroll
    for (int nt = 0; nt < 4; ++nt) {
      f32x4 z = {};
#pragma unroll
      for (int ks = 0; ks < 2; ++ks) {
        int kof = (ks * 32 + h4 * 8) ^ sw;
        bf16x8 kf = *(const bf16x8*)(&Ks[cur][(nt * 16 + l15) * 64 + kof]);
        z = mfma16(kf, qf[ks], z);
      }
      s[nt * 4 + 0] = z[0]; s[nt * 4 + 1] = z[1];
      s[nt * 4 + 2] = z[2]; s[nt * 4 + 3] = z[3];
    }
    if (kt == qt) {
#pragma unroll
      for (int nt = 0; nt < 4; ++nt)
#pragma unroll
        for (int r = 0; r < 4; ++r) {
          int key = q0 + nt * 16 + (h4 << 2) + r;
          if (key > qg) s[nt * 4 + r] = -3e38f;
        }
    }
    float pmax = s[0];
#pragma unroll
    for (int i = 1; i < 16; ++i) pmax = fmaxf(pmax, s[i]);
    pmax = fmaxf(pmax, __shfl_xor(pmax, 16));
    pmax = fmaxf(pmax, __shfl_xor(pmax, 32));
    if (!__all(pmax <= mrow + 11.5f)) {
      float mnew = fmaxf(mrow, pmax);
      float dl = mrow - mnew;
      mrow = mnew;
      lrow *= fexp2(dl);
#pragma unroll
      for (int r = 0; r < 4; ++r) {
        float ar = fexp2(__shfl(dl, (h4 << 2) + r, 16));
#pragma unroll
        for (int d = 0; d < 4; ++d) o[d][r] *= ar;
      }
    }
    float sum = 0.0f;
#pragma unroll
    for (int i = 0; i < 16; ++i) { s[i] = fexp2(s[i] - mrow); sum += s[i]; }
    lrow += sum;
    {
      unsigned short* pr = &Ps[wid][l15 * 72 + (h4 << 2)];
#pragma unroll
      for (int nt = 0; nt < 4; ++nt) {
        uint2 w;
        w.x = pkbf(s[4 * nt], s[4 * nt + 1]);
        w.y = pkbf(s[4 * nt + 2], s[4 * nt + 3]);
        *(uint2*)(pr + nt * 16) = w;
      }
    }
#pragma unroll
    for (int ks = 0; ks < 2; ++ks) {
      bf16x8 pf = *(const bf16x8*)(&Ps[wid][l15 * 72 + ks * 32 + (h4 << 3)]);
      int kof = (ks * 32 + h4 * 8) ^ sw;
#pragma unroll
      for (int d = 0; d < 4; ++d) {
        bf16x8 vf = *(const bf16x8*)(&Vs[cur][(d * 16 + l15) * 64 + kof]);
        o[d] = mfma16(pf, vf, o[d]);
      }
    }
    __builtin_amdgcn_s_barrier();
    if (kt + 2 <= qt) {
      stage(kt + 2, cur);
      asm volatile("s_waitcnt vmcnt(4)" ::: "memory");
    } else if (kt + 1 <= qt) {
      asm volatile("s_waitcnt vmcnt(0)" ::: "memory");
    }
    __builtin_amdgcn_s_barrier();
  }
  lrow += __shfl_xor(lrow, 16);
  lrow += __shfl_xor(lrow, 32);
  float inv = 1.0f / lrow;
#pragma unroll
  for (int r = 0; r < 4; ++r) {
    float invr = __shfl(inv, (h4 << 2) + r, 16);
#pragma unroll
    for (int d = 0; d < 4; ++d)
      ctx[((size_t)b * 2048 + (rowb + r)) * 1024 + hh * 64 + d * 16 + l15] = f2bf(o[d][r] * invr);
  }
}

extern "C" void kernel_launch(void* const* d_in, const int* in_sizes, int n_in,
                              void* d_out, int out_size, void* d_ws, size_t ws_size,
                              hipStream_t stream) {
  (void)in_sizes; (void)n_in; (void)out_size; (void)ws_size;
  const float* in_f = (const float*)d_in[0];
  const int* pos    = (const int*)d_in[1];
  const float* q_w  = (const float*)d_in[2];
  const float* k_w  = (const float*)d_in[3];
  const float* v_w  = (const float*)d_in[4];
  const float* o_w  = (const float*)d_in[5];
  const float* ln1  = (const float*)d_in[6];
  const float* ln2  = (const float*)d_in[7];
  const float* w1   = (const float*)d_in[8];
  const float* w2   = (const float*)d_in[9];
  const float* w3   = (const float*)d_in[10];
  float* out = (float*)d_out;

  unsigned short* ws = (unsigned short*)d_ws;
  unsigned short* wb   = ws;
  unsigned short* wqkb = wb;                // 2M
  unsigned short* wvb  = wb + 2097152;      // 1M
  unsigned short* wob  = wb + 3145728;      // 1M
  unsigned short* w2b  = wb + 4194304;      // 4M
  unsigned short* w13b = wb + 8388608;      // 8M (row-interleaved w1/w3)
  unsigned short* xn   = ws + 16777216;
  unsigned short* qb   = ws + 20971520;
  unsigned short* kb   = ws + 25165824;     // must be qb + 4194304
  unsigned short* vb   = ws + 29360128;     // V^T [bh][64][2048]
  unsigned short* cx   = ws + 33554432;
  unsigned short* partb = ws + 20971520;    // 16M u16 bf16 partials, aliases qb..cx (dead by w2)
  unsigned short* hb   = ws + 54525952;

  CvtArgs ca;
  ca.src[0] = q_w; ca.src[1] = k_w; ca.src[2] = v_w; ca.src[3] = o_w;
  ca.src[4] = w2;  ca.src[5] = w1;  ca.src[6] = w3;
  ca.cum[0] = 0;        ca.cum[1] = 1048576;  ca.cum[2] = 2097152;  ca.cum[3] = 3145728;
  ca.cum[4] = 4194304;  ca.cum[5] = 8388608;  ca.cum[6] = 12582912; ca.cum[7] = 16777216;
  cvt_all<<<16384, 256, 0, stream>>>(ca, wb);

  rmsnorm_k<<<4096, 256, 0, stream>>>(in_f, ln1, xn);

  gemm8_qkv<<<192, 512, 0, stream>>>(xn, wqkb, wvb, qb, vb);

  rope2_k<<<8192, 256, 0, stream>>>(qb, kb, pos);

  attn_k<<<1024, 256, 0, stream>>>(qb, kb, vb, cx);

  gemm_res<1024><<<dim3(32, 8), 256, 0, stream>>>(cx, wob, out, in_f);

  rmsnorm_k<<<4096, 256, 0, stream>>>(out, ln2, xn);

  // fused w1+w3 SwiGLU (2-phase, measured-best): M=4096, N=8192 -> hb bf16
  swiglu2_k<<<dim3(32, 64), 256, 0, stream>>>(xn, w13b, hb);

  // w2 split-K=4 (8-phase, measured-best), bf16 partials
  gemm8_k<5><<<dim3(64, 4), 512, 0, stream>>>(hb, 4096, w2b, 4096, 16, 1024, 16, partb);

  reduce_k<<<4096, 256, 0, stream>>>(out, partb);
}

// Round 17
// 282.024 us; speedup vs baseline: 1.0143x; 1.0108x over previous
//
#include <hip/hip_runtime.h>
#include <hip/hip_bf16.h>

typedef __attribute__((ext_vector_type(8))) __bf16 bf16x8;
typedef __attribute__((ext_vector_type(4))) float f32x4;

#define DEV static __device__ __forceinline__

DEV unsigned short f2bf(float f) {
  __bf16 h = (__bf16)f;
  union { __bf16 h; unsigned short u; } v; v.h = h;
  return v.u;
}
DEV float bf2f(unsigned short h) {
  union { unsigned int u; float f; } v; v.u = ((unsigned int)h) << 16;
  return v.f;
}
DEV unsigned pkbf(float lo, float hi) {
  union { __bf16 h[2]; unsigned u; } v;
  v.h[0] = (__bf16)lo; v.h[1] = (__bf16)hi;
  return v.u;
}
DEV f32x4 mfma16(bf16x8 a, bf16x8 b, f32x4 c) {
  return __builtin_amdgcn_mfma_f32_16x16x32_bf16(a, b, c, 0, 0, 0);
}
DEV void gload_lds16(const void* g, void* l) {
  __builtin_amdgcn_global_load_lds((__attribute__((address_space(1))) void*)g,
                                   (__attribute__((address_space(3))) void*)l,
                                   16, 0, 0);
}
DEV float fexp2(float x) { return exp2f(x); }

// ---------------- fused f32 -> bf16 convert of all 7 weights ----------------
// regions: 0 q_w 1 k_w 2 v_w 3 o_w 4 w2 (linear) | 5 w1, 6 w3 (row-interleaved into w13)
struct CvtArgs { const float* src[7]; int cum[8]; };
__global__ __launch_bounds__(256) void cvt_all(CvtArgs a, unsigned short* __restrict__ dst) {
  int i = (blockIdx.x * 256 + threadIdx.x) * 4;
  if (i >= a.cum[7]) return;
  int w = 0;
#pragma unroll 7
  for (int t = 0; t < 7; ++t) if (i >= a.cum[t + 1]) w = t + 1;
  int local = i - a.cum[w];
  int di;
  if (w == 5)      di = 8388608 + ((local >> 10) << 11) + (local & 1023);          // w1 -> row 2f
  else if (w == 6) di = 8388608 + ((local >> 10) << 11) + 1024 + (local & 1023);   // w3 -> row 2f+1
  else             di = i;
  float4 v = *(const float4*)(a.src[w] + local);
  dst[di + 0] = f2bf(v.x);
  dst[di + 1] = f2bf(v.y);
  dst[di + 2] = f2bf(v.z);
  dst[di + 3] = f2bf(v.w);
}

// ---------------- RMSNorm: fp32 in -> bf16 out (D=1024) ----------------
__global__ __launch_bounds__(256) void rmsnorm_k(const float* __restrict__ x,
                                                 const float* __restrict__ w,
                                                 unsigned short* __restrict__ out) {
  int row = blockIdx.x;
  int tid = threadIdx.x;
  const float* xr = x + (size_t)row * 1024;
  float4 v = *(const float4*)(xr + tid * 4);
  float ss = v.x * v.x + v.y * v.y + v.z * v.z + v.w * v.w;
#pragma unroll
  for (int m = 32; m >= 1; m >>= 1) ss += __shfl_xor(ss, m);
  __shared__ float red[4];
  int wid = tid >> 6;
  if ((tid & 63) == 0) red[wid] = ss;
  __syncthreads();
  float tot = red[0] + red[1] + red[2] + red[3];
  float rs = rsqrtf(tot * (1.0f / 1024.0f) + 1e-5f);
  float4 wv = *(const float4*)(w + tid * 4);
  unsigned short* o = out + (size_t)row * 1024 + tid * 4;
  o[0] = f2bf(v.x * rs * wv.x);
  o[1] = f2bf(v.y * rs * wv.y);
  o[2] = f2bf(v.z * rs * wv.z);
  o[3] = f2bf(v.w * rs * wv.w);
}

// ---------------- RoPE in-place: one thread rotates q AND k ----------------
__global__ __launch_bounds__(256) void rope2_k(unsigned short* __restrict__ q,
                                               unsigned short* __restrict__ k,
                                               const int* __restrict__ pos) {
  int idx = blockIdx.x * 256 + threadIdx.x;  // 2,097,152 threads
  int i = idx & 31;
  int s = (idx >> 5) & 2047;
  int bh = idx >> 16;
  int b = bh >> 4;
  float p = (float)pos[b * 2048 + s];
  float inv = exp2f(-(float)i * 0.4152410118609203f);
  float ang = p * inv;
  float sn = sinf(ang), cs = cosf(ang);
  size_t base = (((size_t)bh * 2048) + s) * 64 + 2 * i;
  float q1 = bf2f(q[base]), q2 = bf2f(q[base + 1]);
  q[base]     = f2bf(q1 * cs - q2 * sn);
  q[base + 1] = f2bf(q1 * sn + q2 * cs);
  float k1 = bf2f(k[base]), k2 = bf2f(k[base + 1]);
  k[base]     = f2bf(k1 * cs - k2 * sn);
  k[base + 1] = f2bf(k1 * sn + k2 * cs);
}

// ================= 256x256 8-phase GEMM =================
// MODE 0: QK scatter; MODE 1: V^T scatter; MODE 2: fp32 resid add;
// MODE 5: bf16 partial (outb pre-offset by z); MODE 6: fused SwiGLU (N=8192 interleaved)
template <int MODE>
DEV void gemm8_body(const unsigned short* __restrict__ A, int lda,
                    const unsigned short* __restrict__ B, int ldb,
                    int bm, int bn, int kbase, int nt,
                    unsigned short* __restrict__ outb, float* __restrict__ outf,
                    const float* __restrict__ resid,
                    unsigned short* As, unsigned short* Bs) {
  const int tid = threadIdx.x;
  const int lane = tid & 63, wid = tid >> 6;
  const int wr = wid >> 2, wc = wid & 3;
  const int m0 = bm * 256, n0 = bn * 256;

  const int r0 = tid >> 2, r1 = 128 + (tid >> 2), cc = tid & 3;
  const int sc0 = (cc ^ ((r0 >> 1) & 3)) * 8;
  const int sc1 = (cc ^ ((r1 >> 1) & 3)) * 8;
  const size_t arow0 = (size_t)(m0 + r0) * lda, arow1 = (size_t)(m0 + r1) * lda;
  const size_t brow0 = (size_t)(n0 + r0) * ldb, brow1 = (size_t)(n0 + r1) * ldb;
  const int du0 = tid * 8, du1 = (512 + tid) * 8;

  auto stA = [&](int t, int kh) {
    unsigned short* d = As + ((((t & 1) << 1) | kh) * 8192);
    const unsigned short* s = A + kbase + t * 64 + kh * 32;
    gload_lds16(s + arow0 + sc0, d + du0);
    gload_lds16(s + arow1 + sc1, d + du1);
  };
  auto stB = [&](int t, int kh) {
    unsigned short* d = Bs + ((((t & 1) << 1) | kh) * 8192);
    const unsigned short* s = B + kbase + t * 64 + kh * 32;
    gload_lds16(s + brow0 + sc0, d + du0);
    gload_lds16(s + brow1 + sc1, d + du1);
  };

  const int fcol = ((lane >> 4) ^ ((lane >> 1) & 3)) * 8;
  const int frow = lane & 15;
  const int abase = (wr * 128 + frow) * 32 + fcol;
  const int bbase = (wc * 64 + frow) * 32 + fcol;

  f32x4 acc[8][4] = {};
  bf16x8 a[4], b[4];

#define LOADA(buf, ks, mh) { const unsigned short* p_ = As + (((buf) << 1) | (ks)) * 8192 + abase + (mh) * 2048; \
  a[0] = *(const bf16x8*)(p_); a[1] = *(const bf16x8*)(p_ + 512); \
  a[2] = *(const bf16x8*)(p_ + 1024); a[3] = *(const bf16x8*)(p_ + 1536); }
#define LOADB(buf, ks) { const unsigned short* p_ = Bs + (((buf) << 1) | (ks)) * 8192 + bbase; \
  b[0] = *(const bf16x8*)(p_); b[1] = *(const bf16x8*)(p_ + 512); \
  b[2] = *(const bf16x8*)(p_ + 1024); b[3] = *(const bf16x8*)(p_ + 1536); }
#define MFMAQ(mh) { _Pragma("unroll") for (int fi = 0; fi < 4; ++fi) \
  _Pragma("unroll") for (int j = 0; j < 4; ++j) \
    acc[(mh) * 4 + fi][j] = mfma16(a[fi], b[j], acc[(mh) * 4 + fi][j]); }
#define LGK0() { asm volatile("s_waitcnt lgkmcnt(0)" ::: "memory"); }

  stA(0, 0); stB(0, 0); stA(0, 1); stB(0, 1);
  stA(1, 0); stB(1, 0);
  asm volatile("s_waitcnt vmcnt(4)" ::: "memory");
  __builtin_amdgcn_s_barrier();

  for (int t = 0; t < nt; ++t) {
    const int buf = t & 1;
    LOADA(buf, 0, 0); LOADB(buf, 0);
    if (t + 1 < nt) stA(t + 1, 1);
    __builtin_amdgcn_s_barrier();
    LGK0();
    __builtin_amdgcn_s_setprio(1); MFMAQ(0); __builtin_amdgcn_s_setprio(0);
    __builtin_amdgcn_s_barrier();
    LOADA(buf, 0, 1);
    if (t + 1 < nt) stB(t + 1, 1);
    __builtin_amdgcn_s_barrier();
    LGK0();
    __builtin_amdgcn_s_setprio(1); MFMAQ(1); __builtin_amdgcn_s_setprio(0);
    __builtin_amdgcn_s_barrier();
    LOADA(buf, 1, 0); LOADB(buf, 1);
    if (t + 2 < nt) stA(t + 2, 0);
    __builtin_amdgcn_s_barrier();
    LGK0();
    __builtin_amdgcn_s_setprio(1); MFMAQ(0); __builtin_amdgcn_s_setprio(0);
    __builtin_amdgcn_s_barrier();
    LOADA(buf, 1, 1);
    if (t + 2 < nt) stB(t + 2, 0);
    __builtin_amdgcn_s_barrier();
    LGK0();
    __builtin_amdgcn_s_setprio(1); MFMAQ(1); __builtin_amdgcn_s_setprio(0);
    if (t + 1 < nt) {
      if (t + 2 < nt) { asm volatile("s_waitcnt vmcnt(4)" ::: "memory"); }
      else            { asm volatile("s_waitcnt vmcnt(0)" ::: "memory"); }
      __builtin_amdgcn_s_barrier();
    }
  }
#undef LOADA
#undef LOADB
#undef MFMAQ
#undef LGK0

#pragma unroll
  for (int i = 0; i < 8; ++i)
#pragma unroll
    for (int j = 0; j < 4; ++j)
#pragma unroll
      for (int r = 0; r < 4; ++r) {
        int m = m0 + wr * 128 + i * 16 + ((lane >> 4) << 2) + r;
        int n = n0 + wc * 64 + j * 16 + (lane & 15);
        float v = acc[i][j][r];
        if (MODE == 0) {
          unsigned short* dst = outb + ((n >= 1024) ? 4194304 : 0);
          int nn = n & 1023;
          int bb = m >> 11, s = m & 2047, hh = nn >> 6, dd = nn & 63;
          dst[(((size_t)bb * 16 + hh) * 2048 + s) * 64 + dd] = f2bf(v);
        } else if (MODE == 1) {
          int hh = m >> 6, dd = m & 63, bb = n >> 11, s = n & 2047;
          outb[(((size_t)bb * 16 + hh) * 64 + dd) * 2048 + s] = f2bf(v);
        } else if (MODE == 2) {
          size_t idx = (size_t)m * 1024 + n;
          outf[idx] = resid[idx] + v;
        } else if (MODE == 5) {
          outb[(size_t)m * 1024 + n] = f2bf(v);
        } else {  // MODE 6: fused SwiGLU; even lane=g(w1 row), odd lane=u(w3 row)
          float other = __shfl_xor(v, 1);
          if (!(lane & 1)) {
            float hv = v / (1.0f + __expf(-v)) * other;
            outb[(size_t)m * 4096 + (n >> 1)] = f2bf(hv);
          }
        }
      }
}

DEV void swz_map(int bid, int nwg, int MT, int& bm, int& bn) {
  int cpx = nwg >> 3;
  int sw = (bid & 7) * cpx + (bid >> 3);
  bm = sw % MT;
  bn = sw / MT;
}

template <int MODE>
__global__ __launch_bounds__(512, 2) void gemm8_k(const unsigned short* __restrict__ A, int lda,
                                                  const unsigned short* __restrict__ B, int ldb,
                                                  int MT, int kz, int nt,
                                                  unsigned short* __restrict__ outb,
                                                  float* __restrict__ outf,
                                                  const float* __restrict__ resid) {
  __shared__ __align__(16) unsigned short lds[65536];
  int bm, bn;
  swz_map(blockIdx.x, gridDim.x, MT, bm, bn);
  int kb = kz * blockIdx.y;
  unsigned short* ob = outb;
  if (MODE == 5) ob += (size_t)blockIdx.y * 4194304;
  gemm8_body<MODE>(A, lda, B, ldb, bm, bn, kb, nt, ob, outf, resid, lds, lds + 32768);
}

__global__ __launch_bounds__(512, 2) void gemm8_qkv(const unsigned short* __restrict__ xn,
                                                    const unsigned short* __restrict__ wqk,
                                                    const unsigned short* __restrict__ wv,
                                                    unsigned short* __restrict__ qk_out,
                                                    unsigned short* __restrict__ vt_out) {
  __shared__ __align__(16) unsigned short lds[65536];
  int bid = blockIdx.x;
  if (bid < 128) {
    int bm, bn;
    swz_map(bid, 128, 16, bm, bn);
    gemm8_body<0>(xn, 1024, wqk, 1024, bm, bn, 0, 16, qk_out, nullptr, nullptr, lds, lds + 32768);
  } else {
    bid -= 128;
    int bm, bn;
    swz_map(bid, 64, 4, bm, bn);
    gemm8_body<1>(wv, 1024, xn, 1024, bm, bn, 0, 16, vt_out, nullptr, nullptr, lds, lds + 32768);
  }
}

// ---------------- 128x128 2-phase GEMM, fp32 out = resid + acc (N=1024) ----------------
template <int K>
__global__ __launch_bounds__(256) void gemm_res(const unsigned short* __restrict__ A,
                                                const unsigned short* __restrict__ Bw,
                                                float* __restrict__ outf,
                                                const float* __restrict__ resid) {
  __shared__ __align__(16) unsigned short As[128 * 64];
  __shared__ __align__(16) unsigned short Bs[128 * 64];
  const int N = 1024;
  const int tid = threadIdx.x;
  const int wid = tid >> 6, lane = tid & 63;
  const int wr = wid >> 1, wc = wid & 1;
  const int m0 = blockIdx.x * 128, n0 = blockIdx.y * 128;
  const int sw = (lane & 7) * 8;
  f32x4 acc[4][4] = {};

  for (int k0 = 0; k0 < K; k0 += 64) {
    __syncthreads();
#pragma unroll
    for (int it = 0; it < 4; ++it) {
      int c = wid * 4 + it;
      int row = c * 8 + (lane >> 3);
      int col = ((lane & 7) ^ (row & 7)) * 8;
      gload_lds16(A + (size_t)(m0 + row) * K + k0 + col, As + c * 512);
      gload_lds16(Bw + (size_t)(n0 + row) * K + k0 + col, Bs + c * 512);
    }
    asm volatile("s_waitcnt vmcnt(0)" ::: "memory");
    __syncthreads();
#pragma unroll
    for (int kk = 0; kk < 2; ++kk) {
      const int kof = (kk * 32 + (lane >> 4) * 8) ^ sw;
      bf16x8 af[4], bfr[4];
#pragma unroll
      for (int i = 0; i < 4; ++i) {
        af[i]  = *(const bf16x8*)(As + (wr * 64 + i * 16 + (lane & 15)) * 64 + kof);
        bfr[i] = *(const bf16x8*)(Bs + (wc * 64 + i * 16 + (lane & 15)) * 64 + kof);
      }
#pragma unroll
      for (int i = 0; i < 4; ++i)
#pragma unroll
        for (int j = 0; j < 4; ++j) acc[i][j] = mfma16(af[i], bfr[j], acc[i][j]);
    }
  }
  const int rb = m0 + wr * 64 + ((lane >> 4) * 4);
  const int cb = n0 + wc * 64 + (lane & 15);
#pragma unroll
  for (int i = 0; i < 4; ++i)
#pragma unroll
    for (int r = 0; r < 4; ++r) {
      int m = rb + i * 16 + r;
#pragma unroll
      for (int j = 0; j < 4; ++j) {
        size_t idx = (size_t)m * N + cb + j * 16;
        outf[idx] = resid[idx] + acc[i][j][r];
      }
    }
}

// ---------------- w2 split-K reduce (bf16 partials) ----------------
__global__ __launch_bounds__(256) void reduce_k(float* __restrict__ out,
                                                const unsigned short* __restrict__ partb) {
  int i = (blockIdx.x * 256 + threadIdx.x) * 4;
  float4 o = *(const float4*)(out + i);
#pragma unroll
  for (int s = 0; s < 4; ++s) {
    uint2 w = *(const uint2*)(partb + (size_t)s * 4194304 + i);
    o.x += bf2f((unsigned short)(w.x & 0xffff));
    o.y += bf2f((unsigned short)(w.x >> 16));
    o.z += bf2f((unsigned short)(w.y & 0xffff));
    o.w += bf2f((unsigned short)(w.y >> 16));
  }
  *(float4*)(out + i) = o;
}

// ---------------- Flash attention: swapped-QK 16x16, dbuf, in-reg softmax ----------------
__global__ __launch_bounds__(256) void attn_k(const unsigned short* __restrict__ q,
                                              const unsigned short* __restrict__ k,
                                              const unsigned short* __restrict__ vt,
                                              unsigned short* __restrict__ ctx) {
  __shared__ __align__(16) unsigned short Ks[2][4096];
  __shared__ __align__(16) unsigned short Vs[2][4096];
  __shared__ __align__(16) unsigned short Ps[4][16 * 72];
  const int bid = blockIdx.x;                       // 1024 blocks
  const int bh = (bid & 7) * 4 + ((bid >> 3) & 3);  // XCD-pinned: 4 heads/XCD
  const int qt = 31 - (bid >> 5);                   // longest first
  const int tid = threadIdx.x, wid = tid >> 6, lane = tid & 63;
  const size_t bhS = (size_t)bh * 2048;
  const size_t bhD = (size_t)bh * 64 * 2048;
  const int b = bh >> 4, hh = bh & 15;
  const int sw = (lane & 7) * 8;
  const int h4 = lane >> 4, l15 = lane & 15;
  const float SC2 = 0.18033688011112042f;  // 0.125 * log2(e)

  const int c0 = wid * 2, c1 = wid * 2 + 1;
  const int row0 = c0 * 8 + (lane >> 3), row1 = c1 * 8 + (lane >> 3);
  const int col0 = ((lane & 7) ^ (row0 & 7)) * 8;
  const int col1 = ((lane & 7) ^ (row1 & 7)) * 8;

  auto stage = [&](int kt, int buf) {
    gload_lds16(k + (bhS + kt * 64 + row0) * 64 + col0, &Ks[buf][c0 * 512]);
    gload_lds16(k + (bhS + kt * 64 + row1) * 64 + col1, &Ks[buf][c1 * 512]);
    gload_lds16(vt + bhD + (size_t)row0 * 2048 + kt * 64 + col0, &Vs[buf][c0 * 512]);
    gload_lds16(vt + bhD + (size_t)row1 * 2048 + kt * 64 + col1, &Vs[buf][c1 * 512]);
  };

  const int q0 = qt * 64;
  bf16x8 qf[2];
  {
    const unsigned short* qp = q + (bhS + q0 + wid * 16 + l15) * 64 + h4 * 8;
    qf[0] = *(const bf16x8*)qp;
    qf[1] = *(const bf16x8*)(qp + 32);
#pragma unroll
    for (int jj = 0; jj < 8; ++jj) {
      qf[0][jj] = (__bf16)((float)qf[0][jj] * SC2);
      qf[1][jj] = (__bf16)((float)qf[1][jj] * SC2);
    }
  }
  float mrow = -1e30f, lrow = 0.0f;
  f32x4 o[4] = {};
  const int qg = q0 + wid * 16 + l15;          // lane's own q (S column)
  const int rowb = q0 + wid * 16 + (h4 << 2);  // output q rows

  stage(0, 0);
  if (qt > 0) { stage(1, 1); asm volatile("s_waitcnt vmcnt(4)" ::: "memory"); }
  else        {              asm volatile("s_waitcnt vmcnt(0)" ::: "memory"); }
  __builtin_amdgcn_s_barrier();

  for (int kt = 0; kt <= qt; ++kt) {
    const int cur = kt & 1;
    float s[16];
#pragma unroll
    for (int nt = 0; nt < 4; ++nt) {
      f32x4 z = {};
#pragma unroll
      for (int ks = 0; ks < 2; ++ks) {
        int kof = (ks * 32 + h4 * 8) ^ sw;
        bf16x8 kf = *(const bf16x8*)(&Ks[cur][(nt * 16 + l15) * 64 + kof]);
        z = mfma16(kf, qf[ks], z);
      }
      s[nt * 4 + 0] = z[0]; s[nt * 4 + 1] = z[1];
      s[nt * 4 + 2] = z[2]; s[nt * 4 + 3] = z[3];
    }
    if (kt == qt) {
#pragma unroll
      for (int nt = 0; nt < 4; ++nt)
#pragma unroll
        for (int r = 0; r < 4; ++r) {
          int key = q0 + nt * 16 + (h4 << 2) + r;
          if (key > qg) s[nt * 4 + r] = -3e38f;
        }
    }
    float pmax = s[0];
#pragma unroll
    for (int i = 1; i < 16; ++i) pmax = fmaxf(pmax, s[i]);
    pmax = fmaxf(pmax, __shfl_xor(pmax, 16));
    pmax = fmaxf(pmax, __shfl_xor(pmax, 32));
    if (!__all(pmax <= mrow + 11.5f)) {
      float mnew = fmaxf(mrow, pmax);
      float dl = mrow - mnew;
      mrow = mnew;
      lrow *= fexp2(dl);
#pragma unroll
      for (int r = 0; r < 4; ++r) {
        float ar = fexp2(__shfl(dl, (h4 << 2) + r, 16));
#pragma unroll
        for (int d = 0; d < 4; ++d) o[d][r] *= ar;
      }
    }
    float sum = 0.0f;
#pragma unroll
    for (int i = 0; i < 16; ++i) { s[i] = fexp2(s[i] - mrow); sum += s[i]; }
    lrow += sum;
    {
      unsigned short* pr = &Ps[wid][l15 * 72 + (h4 << 2)];
#pragma unroll
      for (int nt = 0; nt < 4; ++nt) {
        uint2 w;
        w.x = pkbf(s[4 * nt], s[4 * nt + 1]);
        w.y = pkbf(s[4 * nt + 2], s[4 * nt + 3]);
        *(uint2*)(pr + nt * 16) = w;
      }
    }
#pragma unroll
    for (int ks = 0; ks < 2; ++ks) {
      bf16x8 pf = *(const bf16x8*)(&Ps[wid][l15 * 72 + ks * 32 + (h4 << 3)]);
      int kof = (ks * 32 + h4 * 8) ^ sw;
#pragma unroll
      for (int d = 0; d < 4; ++d) {
        bf16x8 vf = *(const bf16x8*)(&Vs[cur][(d * 16 + l15) * 64 + kof]);
        o[d] = mfma16(pf, vf, o[d]);
      }
    }
    __builtin_amdgcn_s_barrier();
    if (kt + 2 <= qt) {
      stage(kt + 2, cur);
      asm volatile("s_waitcnt vmcnt(4)" ::: "memory");
    } else if (kt + 1 <= qt) {
      asm volatile("s_waitcnt vmcnt(0)" ::: "memory");
    }
    __builtin_amdgcn_s_barrier();
  }
  lrow += __shfl_xor(lrow, 16);
  lrow += __shfl_xor(lrow, 32);
  float inv = 1.0f / lrow;
#pragma unroll
  for (int r = 0; r < 4; ++r) {
    float invr = __shfl(inv, (h4 << 2) + r, 16);
#pragma unroll
    for (int d = 0; d < 4; ++d)
      ctx[((size_t)b * 2048 + (rowb + r)) * 1024 + hh * 64 + d * 16 + l15] = f2bf(o[d][r] * invr);
  }
}

extern "C" void kernel_launch(void* const* d_in, const int* in_sizes, int n_in,
                              void* d_out, int out_size, void* d_ws, size_t ws_size,
                              hipStream_t stream) {
  (void)in_sizes; (void)n_in; (void)out_size; (void)ws_size;
  const float* in_f = (const float*)d_in[0];
  const int* pos    = (const int*)d_in[1];
  const float* q_w  = (const float*)d_in[2];
  const float* k_w  = (const float*)d_in[3];
  const float* v_w  = (const float*)d_in[4];
  const float* o_w  = (const float*)d_in[5];
  const float* ln1  = (const float*)d_in[6];
  const float* ln2  = (const float*)d_in[7];
  const float* w1   = (const float*)d_in[8];
  const float* w2   = (const float*)d_in[9];
  const float* w3   = (const float*)d_in[10];
  float* out = (float*)d_out;

  unsigned short* ws = (unsigned short*)d_ws;
  unsigned short* wb   = ws;
  unsigned short* wqkb = wb;                // 2M
  unsigned short* wvb  = wb + 2097152;      // 1M
  unsigned short* wob  = wb + 3145728;      // 1M
  unsigned short* w2b  = wb + 4194304;      // 4M
  unsigned short* w13b = wb + 8388608;      // 8M (row-interleaved w1/w3)
  unsigned short* xn   = ws + 16777216;
  unsigned short* qb   = ws + 20971520;
  unsigned short* kb   = ws + 25165824;     // must be qb + 4194304
  unsigned short* vb   = ws + 29360128;     // V^T [bh][64][2048]
  unsigned short* cx   = ws + 33554432;
  unsigned short* partb = ws + 20971520;    // 16M u16 bf16 partials, aliases qb..cx (dead by w2)
  unsigned short* hb   = ws + 54525952;

  CvtArgs ca;
  ca.src[0] = q_w; ca.src[1] = k_w; ca.src[2] = v_w; ca.src[3] = o_w;
  ca.src[4] = w2;  ca.src[5] = w1;  ca.src[6] = w3;
  ca.cum[0] = 0;        ca.cum[1] = 1048576;  ca.cum[2] = 2097152;  ca.cum[3] = 3145728;
  ca.cum[4] = 4194304;  ca.cum[5] = 8388608;  ca.cum[6] = 12582912; ca.cum[7] = 16777216;
  cvt_all<<<16384, 256, 0, stream>>>(ca, wb);

  rmsnorm_k<<<4096, 256, 0, stream>>>(in_f, ln1, xn);

  gemm8_qkv<<<192, 512, 0, stream>>>(xn, wqkb, wvb, qb, vb);

  rope2_k<<<8192, 256, 0, stream>>>(qb, kb, pos);

  attn_k<<<1024, 256, 0, stream>>>(qb, kb, vb, cx);

  gemm_res<1024><<<dim3(32, 8), 256, 0, stream>>>(cx, wob, out, in_f);

  rmsnorm_k<<<4096, 256, 0, stream>>>(out, ln2, xn);

  // fused w1+w3 SwiGLU: N=8192 over interleaved weights -> hb bf16 [4096][4096]
  gemm8_k<6><<<512, 512, 0, stream>>>(xn, 1024, w13b, 1024, 16, 0, 16, hb, nullptr, nullptr);

  // w2 split-K=4, bf16 partials
  gemm8_k<5><<<dim3(64, 4), 512, 0, stream>>>(hb, 4096, w2b, 4096, 16, 1024, 16, partb, nullptr, nullptr);

  reduce_k<<<4096, 256, 0, stream>>>(out, partb);
}